// Round 8
// baseline (101.053 us; speedup 1.0000x reference)
//
#include <hip/hip_runtime.h>
#include <hip/hip_bf16.h>

namespace {
constexpr int kB = 2, kW = 5, kS = 5, kQ = 75, kC = 64, kHW = 441;
constexpr int kNP = 448;   // support positions padded (14 * 32)
constexpr int kMP = 448;   // query positions padded (14 col-tiles)
constexpr int kCHUNK = 112;
constexpr int kLDT = 65;   // odd stride -> conflict-free transpose scratch
constexpr int kSupUnits = kB * kW * 4;            // 40
constexpr int kUnits = kSupUnits + kB * kQ * 4;   // 640
constexpr int kTiles = kB * kQ * kW;              // 750
constexpr int kRep = 4;    // DIAGNOSTIC: repeat main pipeline to surface it in rocprof top-5

typedef short bf16x8 __attribute__((ext_vector_type(8)));
typedef float f32x16 __attribute__((ext_vector_type(16)));
typedef __attribute__((address_space(3))) unsigned int lds_u32;
typedef const __attribute__((address_space(1))) unsigned int gbl_u32;
}

// ---- prep (R2-validated, unchanged): shot-mean + L2-norm + transpose -> bf16 ----
__global__ __launch_bounds__(256) void prep_k(const float* __restrict__ sup,
                                              const float* __restrict__ qry,
                                              unsigned short* __restrict__ snT,
                                              unsigned short* __restrict__ qnT) {
  __shared__ float img_t[kCHUNK * kLDT];
  __shared__ float inv[kCHUNK];
  const int tid = threadIdx.x;
  const int blk = blockIdx.x;

  int m0, mcnt;
  unsigned short* dst;
  const bool is_sup = blk < kSupUnits;

  if (is_sup) {
    int bw = blk >> 2, chunk = blk & 3;
    m0 = chunk * kCHUNK;
    mcnt = min(kCHUNK, kHW - m0);
    const float* base = sup + (size_t)bw * kS * kC * kHW;
    for (int i = tid; i < kC * kCHUNK; i += 256) {
      int c = i / kCHUNK, mm = i % kCHUNK;
      float v = 0.f;
      if (mm < mcnt) {
        const float* p = base + (size_t)c * kHW + m0 + mm;
        float s = 0.f;
#pragma unroll
        for (int k = 0; k < kS; ++k) s += p[(size_t)k * kC * kHW];
        v = s * (1.f / kS);
      }
      img_t[mm * kLDT + c] = v;
    }
    dst = snT + (size_t)bw * kNP * kC;
  } else {
    int qb = blk - kSupUnits;
    int bq = qb >> 2, chunk = qb & 3;
    m0 = chunk * kCHUNK;
    mcnt = min(kCHUNK, kHW - m0);
    const float* base = qry + (size_t)bq * kC * kHW;
    for (int i = tid; i < kC * kCHUNK; i += 256) {
      int c = i / kCHUNK, mm = i % kCHUNK;
      img_t[mm * kLDT + c] = (mm < mcnt) ? base[(size_t)c * kHW + m0 + mm] : 0.f;
    }
    dst = qnT + (size_t)bq * kMP * kC;
  }
  __syncthreads();

  if (tid < kCHUNK) {
    float ss = 0.f;
#pragma unroll
    for (int c = 0; c < kC; ++c) { float v = img_t[tid * kLDT + c]; ss += v * v; }
    inv[tid] = 1.f / fmaxf(sqrtf(ss), 1e-12f);
  }
  __syncthreads();

  for (int i8 = tid; i8 < kCHUNK * 8; i8 += 256) {
    int m = i8 >> 3, c8 = (i8 & 7) * 8;
    float sc = inv[m];
    union { unsigned short u[8]; uint4 v; } pk;
#pragma unroll
    for (int j = 0; j < 8; ++j) {
      __hip_bfloat16 o = __float2bfloat16(img_t[m * kLDT + c8 + j] * sc);
      pk.u[j] = *reinterpret_cast<unsigned short*>(&o);
    }
    *reinterpret_cast<uint4*>(dst + ((size_t)(m0 + m) * kC + c8)) = pk.v;
  }
}

// ---- main helpers ----
__device__ __forceinline__ float max16_v(const f32x16& a) {
  float m0 = fmaxf(fmaxf(a[0], a[1]), a[2]);
  float m1 = fmaxf(fmaxf(a[3], a[4]), a[5]);
  float m2 = fmaxf(fmaxf(a[6], a[7]), a[8]);
  float m3 = fmaxf(fmaxf(a[9], a[10]), a[11]);
  float m4 = fmaxf(fmaxf(a[12], a[13]), a[14]);
  return fmaxf(fmaxf(fmaxf(m0, m1), m2), fmaxf(fmaxf(m3, m4), a[15]));
}
__device__ __forceinline__ float max12_v(const f32x16& a) {
  float m0 = fmaxf(fmaxf(a[0], a[1]), a[2]);
  float m1 = fmaxf(fmaxf(a[3], a[4]), a[5]);
  float m2 = fmaxf(fmaxf(a[6], a[7]), a[8]);
  float m3 = fmaxf(fmaxf(a[9], a[10]), a[11]);
  return fmaxf(fmaxf(m0, m1), fmaxf(m2, m3));
}

template <bool TAIL_HALF>
__device__ __forceinline__ void compute_half(const unsigned short* As,
                                             const bf16x8 bf[4][4], int nct,
                                             int lane, float rm[4]) {
  const int lh = lane >> 5;
  const int lm = lane & 31;
  f32x16 z;
#pragma unroll
  for (int r = 0; r < 16; ++r) z[r] = 0.f;

  // runtime loop — full unroll here exceeded 256 VGPR -> spill (R6 lesson)
#pragma unroll 1
  for (int ntl = 0; ntl < 7; ++ntl) {
    bf16x8 af[4];
    int n = ntl * 32 + lm;
#pragma unroll
    for (int kk = 0; kk < 4; ++kk) {
      int k16 = kk * 2 + lh;
      af[kk] = *reinterpret_cast<const bf16x8*>(As + ((size_t)(n * 8 + (k16 ^ (n & 7))) << 3));
    }
    if (!TAIL_HALF || ntl < 6) {
#pragma unroll
      for (int ct = 0; ct < 4; ++ct) {
        if (ct < nct) {
          f32x16 acc = z;
#pragma unroll
          for (int kk = 0; kk < 4; ++kk)
            acc = __builtin_amdgcn_mfma_f32_32x32x16_bf16(af[kk], bf[ct][kk], acc, 0, 0, 0);
          rm[ct] = fmaxf(rm[ct], max16_v(acc));
        }
      }
    } else {
      // global rows 416..447; valid < 441 -> tile row <= 24.
      // row = (r&3)+8*(r>>2)+4*lh: lh0 invalid regs {13,14,15}, lh1 invalid {12..15}
#pragma unroll
      for (int ct = 0; ct < 4; ++ct) {
        if (ct < nct) {
          f32x16 acc = z;
#pragma unroll
          for (int kk = 0; kk < 4; ++kk)
            acc = __builtin_amdgcn_mfma_f32_32x32x16_bf16(af[kk], bf[ct][kk], acc, 0, 0, 0);
          float t = max12_v(acc);
          if (lh == 0) t = fmaxf(t, acc[12]);  // row 24 still valid
          rm[ct] = fmaxf(rm[ct], t);
        }
      }
    }
  }
}

// ---- main (R7-validated logic), run kRep times internally for profiling ----
__global__ __launch_bounds__(256) void dn4_main_k(const unsigned short* __restrict__ qnT,
                                                  const unsigned short* __restrict__ snT,
                                                  float* __restrict__ out) {
  __shared__ __align__(16) unsigned short As[224 * kC];  // 28672 B
  __shared__ float part[4];
  const int tid = threadIdx.x;

  // bijective XCD-chunked mapping (750 = 6*94 + 2*93)
  const int xcd = blockIdx.x & 7, jj = blockIdx.x >> 3;
  const int idx = (xcd < 6) ? xcd * 94 + jj : 564 + (xcd - 6) * 93 + jj;

  const int w = idx % kW;
  const int bq = idx / kW;
  const int b = bq / kQ;

  const int lane = tid & 63;
  const int lh = lane >> 5;
  const int lm = lane & 31;
  const int wid = tid >> 6;
  const int ct0 = (wid < 2) ? wid * 4 : 8 + (wid - 2) * 3;  // col-tiles {4,4,3,3}
  const int nct = (wid < 2) ? 4 : 3;

  const char* sbase = (const char*)(snT + (size_t)(b * kW + w) * kNP * kC);
  const unsigned short* qb = qnT + (size_t)bq * kMP * kC;

#pragma unroll 1
  for (int rep = 0; rep < kRep; ++rep) {   // DIAGNOSTIC repeat (idempotent)
    // stage half 0: LDS linear, source pre-swizzled (involution)
#pragma unroll
    for (int it = 0; it < 7; ++it) {
      int L = it * 256 + tid;
      int srcj = (L & ~7) | ((L & 7) ^ ((L >> 3) & 7));
      __builtin_amdgcn_global_load_lds((gbl_u32*)(sbase + ((size_t)srcj << 4)),
                                       (lds_u32*)((char*)As + ((size_t)L << 4)), 16, 0, 0);
    }

    // query fragments in registers (overlaps with staging)
    bf16x8 bf[4][4];
#pragma unroll
    for (int ct = 0; ct < 4; ++ct) {
      if (ct < nct) {
        int m = (ct0 + ct) * 32 + lm;
#pragma unroll
        for (int kk = 0; kk < 4; ++kk)
          bf[ct][kk] = *reinterpret_cast<const bf16x8*>(qb + (size_t)m * kC + kk * 16 + lh * 8);
      }
    }

    float rm[4] = {-INFINITY, -INFINITY, -INFINITY, -INFINITY};

    __syncthreads();                       // staging half 0 complete (drains vmcnt)
    compute_half<false>(As, bf, nct, lane, rm);
    __syncthreads();                       // all waves done reading half 0

#pragma unroll
    for (int it = 0; it < 7; ++it) {       // stage half 1
      int L = it * 256 + tid;
      int srcj = (L & ~7) | ((L & 7) ^ ((L >> 3) & 7));
      __builtin_amdgcn_global_load_lds((gbl_u32*)(sbase + ((size_t)(1792 + srcj) << 4)),
                                       (lds_u32*)((char*)As + ((size_t)L << 4)), 16, 0, 0);
    }
    __syncthreads();                       // staging half 1 complete
    compute_half<true>(As, bf, nct, lane, rm);

    // combine complementary row-halves, then sum this wave's columns
    float s = 0.f;
#pragma unroll
    for (int ct = 0; ct < 4; ++ct) {
      if (ct < nct) s += fmaxf(rm[ct], __shfl_xor(rm[ct], 32, 64));
    }
#pragma unroll
    for (int off = 1; off < 32; off <<= 1) s += __shfl_xor(s, off, 64);

    if (lane == 0) part[wid] = s;
    __syncthreads();
    if (tid == 0) out[idx] = part[0] + part[1] + part[2] + part[3];
    __syncthreads();                       // part/As safe to reuse next rep
  }
}

extern "C" void kernel_launch(void* const* d_in, const int* in_sizes, int n_in,
                              void* d_out, int out_size, void* d_ws, size_t ws_size,
                              hipStream_t stream) {
  const float* sup = (const float*)d_in[0];
  const float* qry = (const float*)d_in[2];
  float* out = (float*)d_out;

  unsigned short* snT = (unsigned short*)d_ws;                 // 573,440 B
  unsigned short* qnT = snT + (size_t)kB * kW * kNP * kC;      // 8,601,600 B

  prep_k<<<kUnits, 256, 0, stream>>>(sup, qry, snT, qnT);
  dn4_main_k<<<kTiles, 256, 0, stream>>>(qnT, snT, out);
}

// Round 9
// 39.111 us; speedup vs baseline: 2.5838x; 2.5838x over previous
//
#include <hip/hip_runtime.h>
#include <hip/hip_bf16.h>

namespace {
constexpr int kB = 2, kW = 5, kS = 5, kQ = 75, kC = 64, kHW = 441;
constexpr int kNP = 448;   // support positions padded (14 * 32)
constexpr int kMP = 448;   // query positions padded (14 col-tiles)
constexpr int kCHUNK = 112;
constexpr int kLDT = 65;   // odd stride -> conflict-free transpose scratch
constexpr int kSupUnits = kB * kW * 4;            // 40
constexpr int kUnits = kSupUnits + kB * kQ * 4;   // 640
constexpr int kTiles = kB * kQ * kW;              // 750
constexpr int kThreads = 448;                     // 7 waves: 2 col-tiles each, balanced
constexpr int kWaves = 7;

typedef short bf16x8 __attribute__((ext_vector_type(8)));
typedef float f32x16 __attribute__((ext_vector_type(16)));
typedef __attribute__((address_space(3))) unsigned int lds_u32;
typedef const __attribute__((address_space(1))) unsigned int gbl_u32;
}

// ---- prep (R2-validated, unchanged): shot-mean + L2-norm + transpose -> bf16 ----
__global__ __launch_bounds__(256) void prep_k(const float* __restrict__ sup,
                                              const float* __restrict__ qry,
                                              unsigned short* __restrict__ snT,
                                              unsigned short* __restrict__ qnT) {
  __shared__ float img_t[kCHUNK * kLDT];
  __shared__ float inv[kCHUNK];
  const int tid = threadIdx.x;
  const int blk = blockIdx.x;

  int m0, mcnt;
  unsigned short* dst;
  const bool is_sup = blk < kSupUnits;

  if (is_sup) {
    int bw = blk >> 2, chunk = blk & 3;
    m0 = chunk * kCHUNK;
    mcnt = min(kCHUNK, kHW - m0);
    const float* base = sup + (size_t)bw * kS * kC * kHW;
    for (int i = tid; i < kC * kCHUNK; i += 256) {
      int c = i / kCHUNK, mm = i % kCHUNK;
      float v = 0.f;
      if (mm < mcnt) {
        const float* p = base + (size_t)c * kHW + m0 + mm;
        float s = 0.f;
#pragma unroll
        for (int k = 0; k < kS; ++k) s += p[(size_t)k * kC * kHW];
        v = s * (1.f / kS);
      }
      img_t[mm * kLDT + c] = v;
    }
    dst = snT + (size_t)bw * kNP * kC;
  } else {
    int qb = blk - kSupUnits;
    int bq = qb >> 2, chunk = qb & 3;
    m0 = chunk * kCHUNK;
    mcnt = min(kCHUNK, kHW - m0);
    const float* base = qry + (size_t)bq * kC * kHW;
    for (int i = tid; i < kC * kCHUNK; i += 256) {
      int c = i / kCHUNK, mm = i % kCHUNK;
      img_t[mm * kLDT + c] = (mm < mcnt) ? base[(size_t)c * kHW + m0 + mm] : 0.f;
    }
    dst = qnT + (size_t)bq * kMP * kC;
  }
  __syncthreads();

  if (tid < kCHUNK) {
    float ss = 0.f;
#pragma unroll
    for (int c = 0; c < kC; ++c) { float v = img_t[tid * kLDT + c]; ss += v * v; }
    inv[tid] = 1.f / fmaxf(sqrtf(ss), 1e-12f);
  }
  __syncthreads();

  for (int i8 = tid; i8 < kCHUNK * 8; i8 += 256) {
    int m = i8 >> 3, c8 = (i8 & 7) * 8;
    float sc = inv[m];
    union { unsigned short u[8]; uint4 v; } pk;
#pragma unroll
    for (int j = 0; j < 8; ++j) {
      __hip_bfloat16 o = __float2bfloat16(img_t[m * kLDT + c8 + j] * sc);
      pk.u[j] = *reinterpret_cast<unsigned short*>(&o);
    }
    *reinterpret_cast<uint4*>(dst + ((size_t)(m0 + m) * kC + c8)) = pk.v;
  }
}

// ---- main helpers ----
__device__ __forceinline__ float max16_v(const f32x16& a) {
  float m0 = fmaxf(fmaxf(a[0], a[1]), a[2]);
  float m1 = fmaxf(fmaxf(a[3], a[4]), a[5]);
  float m2 = fmaxf(fmaxf(a[6], a[7]), a[8]);
  float m3 = fmaxf(fmaxf(a[9], a[10]), a[11]);
  float m4 = fmaxf(fmaxf(a[12], a[13]), a[14]);
  return fmaxf(fmaxf(fmaxf(m0, m1), m2), fmaxf(fmaxf(m3, m4), a[15]));
}
__device__ __forceinline__ float max12_v(const f32x16& a) {
  float m0 = fmaxf(fmaxf(a[0], a[1]), a[2]);
  float m1 = fmaxf(fmaxf(a[3], a[4]), a[5]);
  float m2 = fmaxf(fmaxf(a[6], a[7]), a[8]);
  float m3 = fmaxf(fmaxf(a[9], a[10]), a[11]);
  return fmaxf(fmaxf(m0, m1), fmaxf(m2, m3));
}

template <bool TAIL_HALF>
__device__ __forceinline__ void compute_half(const unsigned short* As,
                                             const bf16x8 bf[2][4],
                                             int lane, float rm[2]) {
  const int lh = lane >> 5;
  const int lm = lane & 31;
  f32x16 z;
#pragma unroll
  for (int r = 0; r < 16; ++r) z[r] = 0.f;

  // runtime loop — full unroll exceeded 256 VGPR -> spill (R6 lesson)
#pragma unroll 1
  for (int ntl = 0; ntl < 7; ++ntl) {
    bf16x8 af[4];
    int n = ntl * 32 + lm;
#pragma unroll
    for (int kk = 0; kk < 4; ++kk) {
      int k16 = kk * 2 + lh;
      af[kk] = *reinterpret_cast<const bf16x8*>(As + ((size_t)(n * 8 + (k16 ^ (n & 7))) << 3));
    }
    if (!TAIL_HALF || ntl < 6) {
#pragma unroll
      for (int ct = 0; ct < 2; ++ct) {
        f32x16 acc = z;
#pragma unroll
        for (int kk = 0; kk < 4; ++kk)
          acc = __builtin_amdgcn_mfma_f32_32x32x16_bf16(af[kk], bf[ct][kk], acc, 0, 0, 0);
        rm[ct] = fmaxf(rm[ct], max16_v(acc));
      }
    } else {
      // global rows 416..447; valid < 441 -> tile row <= 24.
      // row = (r&3)+8*(r>>2)+4*lh: lh0 invalid regs {13,14,15}, lh1 invalid {12..15}
#pragma unroll
      for (int ct = 0; ct < 2; ++ct) {
        f32x16 acc = z;
#pragma unroll
        for (int kk = 0; kk < 4; ++kk)
          acc = __builtin_amdgcn_mfma_f32_32x32x16_bf16(af[kk], bf[ct][kk], acc, 0, 0, 0);
        float t = max12_v(acc);
        if (lh == 0) t = fmaxf(t, acc[12]);  // row 24 still valid
        rm[ct] = fmaxf(rm[ct], t);
      }
    }
  }
}

// ---- main: 7-wave blocks (2 col-tiles/wave, balanced) for 2x occupancy.
//      R8 diagnostic: 23us/rep at MfmaUtil 35%, Occupancy 16% (grid-limited,
//      3 waves/SIMD). MFMA floor ~8us; more waves -> cross-wave MFMA/VALU overlap. ----
__global__ __launch_bounds__(kThreads) void dn4_main_k(const unsigned short* __restrict__ qnT,
                                                       const unsigned short* __restrict__ snT,
                                                       float* __restrict__ out) {
  __shared__ __align__(16) unsigned short As[224 * kC];  // 28672 B
  __shared__ float part[kWaves];
  const int tid = threadIdx.x;

  // bijective XCD-chunked mapping (750 = 6*94 + 2*93)
  const int xcd = blockIdx.x & 7, jj = blockIdx.x >> 3;
  const int idx = (xcd < 6) ? xcd * 94 + jj : 564 + (xcd - 6) * 93 + jj;

  const int w = idx % kW;
  const int bq = idx / kW;
  const int b = bq / kQ;

  const int lane = tid & 63;
  const int lh = lane >> 5;
  const int lm = lane & 31;
  const int wid = tid >> 6;          // 0..6
  const int ct0 = wid * 2;           // 2 col-tiles per wave, 14 total

  const char* sbase = (const char*)(snT + (size_t)(b * kW + w) * kNP * kC);
  const unsigned short* qb = qnT + (size_t)bq * kMP * kC;

  // stage half 0 (1792 chunks = 4 * 448): LDS linear, source pre-swizzled (involution)
#pragma unroll
  for (int it = 0; it < 4; ++it) {
    int L = it * kThreads + tid;
    int srcj = (L & ~7) | ((L & 7) ^ ((L >> 3) & 7));
    __builtin_amdgcn_global_load_lds((gbl_u32*)(sbase + ((size_t)srcj << 4)),
                                     (lds_u32*)((char*)As + ((size_t)L << 4)), 16, 0, 0);
  }

  // query fragments in registers (overlaps with staging)
  bf16x8 bf[2][4];
#pragma unroll
  for (int ct = 0; ct < 2; ++ct) {
    int m = (ct0 + ct) * 32 + lm;
#pragma unroll
    for (int kk = 0; kk < 4; ++kk)
      bf[ct][kk] = *reinterpret_cast<const bf16x8*>(qb + (size_t)m * kC + kk * 16 + lh * 8);
  }

  float rm[2] = {-INFINITY, -INFINITY};

  __syncthreads();                       // staging half 0 complete (drains vmcnt)
  compute_half<false>(As, bf, lane, rm);
  __syncthreads();                       // all waves done reading half 0

#pragma unroll
  for (int it = 0; it < 4; ++it) {       // stage half 1 (chunks 1792..3583)
    int L = it * kThreads + tid;
    int srcj = (L & ~7) | ((L & 7) ^ ((L >> 3) & 7));
    __builtin_amdgcn_global_load_lds((gbl_u32*)(sbase + ((size_t)(1792 + srcj) << 4)),
                                     (lds_u32*)((char*)As + ((size_t)L << 4)), 16, 0, 0);
  }
  __syncthreads();                       // staging half 1 complete
  compute_half<true>(As, bf, lane, rm);

  // combine complementary row-halves, then sum this wave's 64 columns
  float s = fmaxf(rm[0], __shfl_xor(rm[0], 32, 64)) +
            fmaxf(rm[1], __shfl_xor(rm[1], 32, 64));
#pragma unroll
  for (int off = 1; off < 32; off <<= 1) s += __shfl_xor(s, off, 64);

  if (lane == 0) part[wid] = s;
  __syncthreads();
  if (tid == 0) {
    float t = 0.f;
#pragma unroll
    for (int v = 0; v < kWaves; ++v) t += part[v];
    out[idx] = t;
  }
}

extern "C" void kernel_launch(void* const* d_in, const int* in_sizes, int n_in,
                              void* d_out, int out_size, void* d_ws, size_t ws_size,
                              hipStream_t stream) {
  const float* sup = (const float*)d_in[0];
  const float* qry = (const float*)d_in[2];
  float* out = (float*)d_out;

  unsigned short* snT = (unsigned short*)d_ws;                 // 573,440 B
  unsigned short* qnT = snT + (size_t)kB * kW * kNP * kC;      // 8,601,600 B

  prep_k<<<kUnits, 256, 0, stream>>>(sup, qry, snT, qnT);
  dn4_main_k<<<kTiles, kThreads, 0, stream>>>(qnT, snT, out);
}